// Round 4
// baseline (1005.095 us; speedup 1.0000x reference)
//
#include <hip/hip_runtime.h>
#include <hip/hip_bf16.h>

// ---- problem constants ----
#define GF    7
#define TAPS  25
#define NCHNK 7          // 224/32 channel chunks
#define NTILE 10         // 10 tiles of 6 output rows
#define TROWS 6
#define SROWS 10         // 6 + 4 halo
#define NPOS  360        // 6*60 positions per tile

typedef __attribute__((ext_vector_type(8)))  __bf16 bf16x8;
typedef __attribute__((ext_vector_type(8)))  unsigned short u16x8;
typedef __attribute__((ext_vector_type(16))) float f32x16;

__device__ __forceinline__ f32x16 mfma32(u16x8 a, u16x8 b, f32x16 c) {
  return __builtin_amdgcn_mfma_f32_32x32x16_bf16(
      __builtin_bit_cast(bf16x8, a), __builtin_bit_cast(bf16x8, b), c, 0, 0, 0);
}

// w[o][c][f][kh][kw] f32 -> wt[tap][ck][o][c8] bf16, cc = ck*32+c8 = c*7+f
__global__ void wt_kernel(const float* __restrict__ w, unsigned short* __restrict__ wt) {
  int i = blockIdx.x * 256 + threadIdx.x;
  if (i >= TAPS * NCHNK * 64 * 32) return;
  int c8  = i & 31;
  int o   = (i >> 5) & 63;
  int ck  = (i >> 11) % NCHNK;
  int tap = i / (NCHNK * 64 * 32);
  int cc = ck * 32 + c8;
  int c = cc / GF, f = cc - GF * (cc / GF);
  float v = w[(size_t)o * (32 * GF * TAPS) + c * (GF * TAPS) + f * TAPS + tap];
  __bf16 hb = (__bf16)v;
  wt[i] = __builtin_bit_cast(unsigned short, hb);
}

// Block = (b, g, 6-row tile). 4 waves; wave: 2 m-frags(32 o) x 3 n-frags(32 pos),
// mfma_f32_32x32x16_bf16. A from global (1-tap reg prefetch), B from LDS Xs.
// Xs: 10 rows x 64 cols x 32 ch bf16, XOR-swizzled slots (40960 B -> 4 blocks/CU).
__global__ void __launch_bounds__(256, 4)
conv_kernel(const float* __restrict__ x, const unsigned short* __restrict__ wt,
            const float* __restrict__ bias, const int* __restrict__ idx,
            float* __restrict__ out) {
  __shared__ __align__(16) unsigned short Xs[640 * 32];  // exactly 40960 B

  // XCD-aware swizzle: 1200 = 8 XCDs * 150 contiguous blocks
  const int bid0 = blockIdx.x;
  const int bid  = (bid0 & 7) * 150 + (bid0 >> 3);
  const int tile = bid % NTILE;
  const int g    = (bid / NTILE) % 15;
  const int b    = bid / (NTILE * 15);

  const int tid  = threadIdx.x;
  const int lane = tid & 63;
  const int wv   = tid >> 6;     // wave 0..3 (staging channel-group)
  const int l31  = lane & 31;
  const int hi   = lane >> 5;    // K-half selector
  const int col  = tid & 63;

  // group-gather indices (wave-uniform)
  int gidx[GF];
#pragma unroll
  for (int f = 0; f < GF; ++f) gidx[f] = idx[g * GF + f];

  // n-frag base positions: wave wv owns frags {wv, wv+4, wv+8} of 12 (frag 11 partial)
  int pt0[3];
#pragma unroll
  for (int i = 0; i < 3; ++i) {
    int p  = (4 * i + wv) * 32 + l31;
    int pc = (p < NPOS) ? p : 0;           // clamp; epilogue guards writes
    int ph = pc / 60;
    pt0[i] = ph * 64 + (pc - 60 * ph);
  }

  f32x16 acc[2][3];
#pragma unroll
  for (int m = 0; m < 2; ++m)
#pragma unroll
    for (int i = 0; i < 3; ++i)
#pragma unroll
      for (int r = 0; r < 16; ++r) acc[m][i][r] = 0.f;

  // A-frag lane offset: o = m*32 + l31, c8 = ks*16 + hi*8 + j
  const int alane = l31 * 32 + hi * 8;
  u16x8 wa[2][2], wn[2][2];
  {
    const unsigned short* p = wt + alane;  // tap 0, ck 0
#pragma unroll
    for (int m = 0; m < 2; ++m)
#pragma unroll
      for (int ks = 0; ks < 2; ++ks)
        wn[m][ks] = *reinterpret_cast<const u16x8*>(p + m * 1024 + ks * 16);
  }

  const int r0 = tile * TROWS;

  for (int ck = 0; ck < NCHNK; ++ck) {
    // image plane bases for this wave's 8 staging channels
    int ib[8];
#pragma unroll
    for (int k = 0; k < 8; ++k) {
      int cc = ck * 32 + 8 * wv + k;
      int c = cc / GF, f = cc - GF * c;
      ib[k] = ((b * 32 + c) * 33 + gidx[f]) * 4096;
    }

    __syncthreads();  // everyone done reading previous chunk's Xs
#pragma unroll
    for (int row = 0; row < SROWS; ++row) {
      int ga = (r0 + row) * 64 + col;
      u16x8 pk;
#pragma unroll
      for (int k = 0; k < 8; ++k) {
        float v = x[ib[k] + ga];
        pk[k] = __builtin_bit_cast(unsigned short, (__bf16)v);
      }
      int pos = row * 64 + col;
      *reinterpret_cast<u16x8*>(&Xs[pos * 32 + 8 * (wv ^ ((pos >> 1) & 3))]) = pk;
    }
    __syncthreads();  // Xs ready

    for (int kh = 0; kh < 5; ++kh) {
#pragma unroll
      for (int kw = 0; kw < 5; ++kw) {
        const int tap = kh * 5 + kw;
        // rotate prefetch -> current
#pragma unroll
        for (int m = 0; m < 2; ++m)
#pragma unroll
          for (int ks = 0; ks < 2; ++ks) wa[m][ks] = wn[m][ks];
        // prefetch next tap's A (wraps to next ck; harmless wrap at very end)
        int ntap = tap + 1, nck = ck;
        if (ntap == TAPS) { ntap = 0; nck = (ck + 1 < NCHNK) ? ck + 1 : 0; }
        const unsigned short* p = wt + (((ntap * NCHNK) + nck) << 11) + alane;
#pragma unroll
        for (int m = 0; m < 2; ++m)
#pragma unroll
          for (int ks = 0; ks < 2; ++ks)
            wn[m][ks] = *reinterpret_cast<const u16x8*>(p + m * 1024 + ks * 16);

        const int toff = kh * 64 + kw;
#pragma unroll
        for (int ks = 0; ks < 2; ++ks) {
          u16x8 bf[3];
#pragma unroll
          for (int i = 0; i < 3; ++i) {
            int pt = pt0[i] + toff;
            bf[i] = *reinterpret_cast<const u16x8*>(
                &Xs[pt * 32 + 8 * ((2 * ks + hi) ^ ((pt >> 1) & 3))]);
          }
#pragma unroll
          for (int i = 0; i < 3; ++i)
#pragma unroll
            for (int m = 0; m < 2; ++m)
              acc[m][i] = mfma32(wa[m][ks], bf[i], acc[m][i]);
        }
      }
    }
  }

  // bias into registers (o = m*32 + 4*hi + (r&3) + 8*(r>>2))
  float bv[2][16];
#pragma unroll
  for (int m = 0; m < 2; ++m)
#pragma unroll
    for (int r = 0; r < 16; ++r)
      bv[m][r] = bias[m * 32 + 4 * hi + (r & 3) + 8 * (r >> 2)];

  // epilogue: out[((b*64+o)*15+g)*3600 + tile*360 + p]
#pragma unroll
  for (int i = 0; i < 3; ++i) {
    int p = (4 * i + wv) * 32 + l31;
    if (p < NPOS) {
      const size_t pb = (size_t)tile * NPOS + p;
#pragma unroll
      for (int m = 0; m < 2; ++m)
#pragma unroll
        for (int r = 0; r < 16; ++r) {
          int o = m * 32 + 4 * hi + (r & 3) + 8 * (r >> 2);
          out[((size_t)(b * 64 + o) * 15 + g) * 3600 + pb] = acc[m][i][r] + bv[m][r];
        }
    }
  }
}

extern "C" void kernel_launch(void* const* d_in, const int* in_sizes, int n_in,
                              void* d_out, int out_size, void* d_ws, size_t ws_size,
                              hipStream_t stream) {
  const float* x      = (const float*)d_in[0];
  const float* weight = (const float*)d_in[1];
  const float* bias   = (const float*)d_in[2];
  const int*   idx    = (const int*)d_in[3];
  float* out = (float*)d_out;
  unsigned short* wt = (unsigned short*)d_ws;  // 25*7*64*32*2 = 716800 B

  wt_kernel<<<(TAPS * NCHNK * 64 * 32 + 255) / 256, 256, 0, stream>>>(weight, wt);
  conv_kernel<<<8 * 15 * NTILE, 256, 0, stream>>>(x, wt, bias, idx, out);
}

// Round 5
// 711.181 us; speedup vs baseline: 1.4133x; 1.4133x over previous
//
#include <hip/hip_runtime.h>
#include <hip/hip_bf16.h>

// ---- problem constants ----
#define GF    7
#define TAPS  25
#define NCHNK 7          // 224/32 channel chunks
#define NTILE 15         // tiles of 4 output rows
#define TROWS 4
#define SROWS 8          // 4 + 4 halo
#define RS    68         // Xs row stride: 64 cols + 4 kw-pad

typedef __attribute__((ext_vector_type(8)))  __bf16 bf16x8;
typedef __attribute__((ext_vector_type(8)))  unsigned short u16x8;
typedef __attribute__((ext_vector_type(16))) float f32x16;

__device__ __forceinline__ f32x16 mfma32(u16x8 a, u16x8 b, f32x16 c) {
  return __builtin_amdgcn_mfma_f32_32x32x16_bf16(
      __builtin_bit_cast(bf16x8, a), __builtin_bit_cast(bf16x8, b), c, 0, 0, 0);
}

// w[o][c][f][kh][kw] f32 -> wt[tap][ck][o][c8] bf16, cc = ck*32+c8 = c*7+f
__global__ void wt_kernel(const float* __restrict__ w, unsigned short* __restrict__ wt) {
  int i = blockIdx.x * 256 + threadIdx.x;
  if (i >= TAPS * NCHNK * 64 * 32) return;
  int c8  = i & 31;
  int o   = (i >> 5) & 63;
  int ck  = (i >> 11) % NCHNK;
  int tap = i / (NCHNK * 64 * 32);
  int cc = ck * 32 + c8;
  int c = cc / GF, f = cc - GF * (cc / GF);
  float v = w[(size_t)o * (32 * GF * TAPS) + c * (GF * TAPS) + f * TAPS + tap];
  __bf16 hb = (__bf16)v;
  wt[i] = __builtin_bit_cast(unsigned short, hb);
}

// Block = (b, g, 4-row tile). 4 waves; wave = 2 m-frags(32 o) x 2 n-frags(32 pos),
// mfma_f32_32x32x16_bf16. A from global wt (1-tap register prefetch), B from LDS.
// Xs: 8 rows x 68 pos x 32 ch bf16 (34816 B), XOR-swizzled channel octets.
// N padded to row-halves of 32 (cols 60..63 dummy) -> B-frags never cross rows
// -> conflict-free ds_read_b128.
__global__ void __launch_bounds__(256, 3)
conv_kernel(const float* __restrict__ x, const unsigned short* __restrict__ wt,
            const float* __restrict__ bias, const int* __restrict__ idx,
            float* __restrict__ out) {
  __shared__ __align__(16) unsigned short Xs[SROWS * RS * 32];  // 34816 B

  // XCD-aware bijective swizzle: 1800 = 8 XCDs * 225
  const int bid0 = blockIdx.x;
  const int bid  = (bid0 & 7) * 225 + (bid0 >> 3);
  const int tile = bid % NTILE;
  const int g    = (bid / NTILE) % 15;
  const int b    = bid / (NTILE * 15);

  const int tid  = threadIdx.x;
  const int lane = tid & 63;
  const int wv   = tid >> 6;     // wave 0..3 = staging channel-octet q
  const int l31  = lane & 31;
  const int hi   = lane >> 5;
  const int col  = tid & 63;

  // zero the kw-reach pad (cols 64..67, all rows, all octets) once
  {
    int row = tid >> 5;            // 0..7
    int cp  = 64 + ((tid >> 3) & 3);
    int oct = tid & 7;
    u16x8 z;
#pragma unroll
    for (int j = 0; j < 8; ++j) z[j] = 0;
    *reinterpret_cast<u16x8*>(&Xs[(row * RS + cp) * 32 + 8 * oct]) = z;
  }

  // n-frag bases: wave owns frags {wv, wv+4} of 8; nf = row*2 + half
  int pb[2], rowf[2], half[2];
#pragma unroll
  for (int i = 0; i < 2; ++i) {
    int nf = wv + 4 * i;
    rowf[i] = nf >> 1;
    half[i] = nf & 1;
    pb[i]   = rowf[i] * RS + half[i] * 32 + l31;
  }

  f32x16 acc[2][2];
#pragma unroll
  for (int m = 0; m < 2; ++m)
#pragma unroll
    for (int i = 0; i < 2; ++i)
#pragma unroll
      for (int r = 0; r < 16; ++r) acc[m][i][r] = 0.f;

  // A-frag lane offset: o = m*32 + l31, ch = ks*16 + hi*8 .. +8
  const int alane = l31 * 32 + hi * 8;
  u16x8 wa[2][2], wn[2][2];
  {
    const unsigned short* p = wt + alane;  // tap 0, ck 0
#pragma unroll
    for (int m = 0; m < 2; ++m)
#pragma unroll
      for (int ks = 0; ks < 2; ++ks)
        wn[m][ks] = *reinterpret_cast<const u16x8*>(p + m * 1024 + ks * 16);
  }

  const int r0 = tile * TROWS;

  for (int ck = 0; ck < NCHNK; ++ck) {
    // image plane bases for this wave's 8 staging channels (wave-uniform)
    int ib[8];
#pragma unroll
    for (int k = 0; k < 8; ++k) {
      int cc = ck * 32 + 8 * wv + k;
      int c = cc / GF, f = cc - GF * c;
      ib[k] = ((b * 32 + c) * 33 + idx[g * GF + f]) << 12;
    }

    __syncthreads();  // everyone done reading previous chunk's Xs
#pragma unroll
    for (int row = 0; row < SROWS; ++row) {
      int ga = (r0 + row) * 64 + col;
      u16x8 pk;
#pragma unroll
      for (int k = 0; k < 8; ++k) {
        float v = x[ib[k] + ga];
        pk[k] = __builtin_bit_cast(unsigned short, (__bf16)v);
      }
      int pos = row * RS + col;
      *reinterpret_cast<u16x8*>(&Xs[pos * 32 + 8 * (wv ^ ((pos >> 1) & 3))]) = pk;
    }
    __syncthreads();  // Xs ready

#pragma unroll
    for (int kh = 0; kh < 5; ++kh) {
#pragma unroll
      for (int kw = 0; kw < 5; ++kw) {
        const int tap = kh * 5 + kw;
        // rotate prefetch -> current
#pragma unroll
        for (int m = 0; m < 2; ++m)
#pragma unroll
          for (int ks = 0; ks < 2; ++ks) wa[m][ks] = wn[m][ks];
        // prefetch next tap's A
        int ntap = tap + 1, nck = ck;
        if (ntap == TAPS) { ntap = 0; nck = (ck + 1 < NCHNK) ? ck + 1 : 0; }
        const unsigned short* p = wt + (((ntap * NCHNK) + nck) << 11) + alane;
#pragma unroll
        for (int m = 0; m < 2; ++m)
#pragma unroll
          for (int ks = 0; ks < 2; ++ks)
            wn[m][ks] = *reinterpret_cast<const u16x8*>(p + m * 1024 + ks * 16);

        const int toff = kh * RS + kw;
#pragma unroll
        for (int ks = 0; ks < 2; ++ks) {
          u16x8 bf[2];
#pragma unroll
          for (int i = 0; i < 2; ++i) {
            int pt = pb[i] + toff;
            bf[i] = *reinterpret_cast<const u16x8*>(
                &Xs[pt * 32 + 8 * ((2 * ks + hi) ^ ((pt >> 1) & 3))]);
          }
#pragma unroll
          for (int i = 0; i < 2; ++i)
#pragma unroll
            for (int m = 0; m < 2; ++m)
              acc[m][i] = mfma32(wa[m][ks], bf[i], acc[m][i]);
        }
      }
    }
  }

  // bias into registers (o = m*32 + 4*hi + (r&3) + 8*(r>>2))
  float bv[2][16];
#pragma unroll
  for (int m = 0; m < 2; ++m)
#pragma unroll
    for (int r = 0; r < 16; ++r)
      bv[m][r] = bias[m * 32 + 4 * hi + (r & 3) + 8 * (r >> 2)];

  // epilogue: out[((b*64+o)*15+g)*3600 + (tile*4+row)*60 + col], col<60 valid
#pragma unroll
  for (int i = 0; i < 2; ++i) {
    int colo = half[i] * 32 + l31;
    if (colo < 60) {
      const size_t pbase = (size_t)(tile * TROWS + rowf[i]) * 60 + colo;
#pragma unroll
      for (int m = 0; m < 2; ++m)
#pragma unroll
        for (int r = 0; r < 16; ++r) {
          int o = m * 32 + 4 * hi + (r & 3) + 8 * (r >> 2);
          out[((size_t)(b * 64 + o) * 15 + g) * 3600 + pbase] = acc[m][i][r] + bv[m][r];
        }
    }
  }
}

extern "C" void kernel_launch(void* const* d_in, const int* in_sizes, int n_in,
                              void* d_out, int out_size, void* d_ws, size_t ws_size,
                              hipStream_t stream) {
  const float* x      = (const float*)d_in[0];
  const float* weight = (const float*)d_in[1];
  const float* bias   = (const float*)d_in[2];
  const int*   idx    = (const int*)d_in[3];
  float* out = (float*)d_out;
  unsigned short* wt = (unsigned short*)d_ws;  // 25*7*64*32*2 = 716800 B

  wt_kernel<<<(TAPS * NCHNK * 64 * 32 + 255) / 256, 256, 0, stream>>>(weight, wt);
  conv_kernel<<<8 * 15 * NTILE, 256, 0, stream>>>(x, wt, bias, idx, out);
}

// Round 6
// 354.255 us; speedup vs baseline: 2.8372x; 2.0075x over previous
//
#include <hip/hip_runtime.h>
#include <hip/hip_bf16.h>

// ---- problem constants ----
#define GF    7
#define TAPS  25
#define NCHNK 7          // 224/32 channel chunks
#define NTILE 15         // tiles of 4 output rows
#define TROWS 4
#define SROWS 8          // 4 + 4 halo
#define NGRP  35         // NCHNK * 5 kh-groups

typedef __attribute__((ext_vector_type(8)))  __bf16 bf16x8;
typedef __attribute__((ext_vector_type(8)))  unsigned short u16x8;
typedef __attribute__((ext_vector_type(16))) float f32x16;

__device__ __forceinline__ f32x16 mfma32(u16x8 a, u16x8 b, f32x16 c) {
  return __builtin_amdgcn_mfma_f32_32x32x16_bf16(
      __builtin_bit_cast(bf16x8, a), __builtin_bit_cast(bf16x8, b), c, 0, 0, 0);
}

// async global->LDS, 16B per lane; LDS dest = wave-uniform base + lane*16
__device__ __forceinline__ void glds16(const unsigned short* g, unsigned short* l) {
  __builtin_amdgcn_global_load_lds(
      (__attribute__((address_space(1))) void*)g,
      (__attribute__((address_space(3))) void*)l, 16, 0, 0);
}

// w[o][c][f][kh][kw] f32 -> wt[tap][ck][o][s][e] bf16 with BAKED bank swizzle:
// stored channel cc = ck*32 + 8*(s ^ ((o>>1)&3)) + e   (verified in R3)
// In-kernel A-read at slot = want ^ ((o>>1)&3) is then conflict-free with a
// LINEAR LDS copy (global_load_lds-compatible).
__global__ void wt_kernel(const float* __restrict__ w, unsigned short* __restrict__ wt) {
  int i = blockIdx.x * 256 + threadIdx.x;
  if (i >= TAPS * NCHNK * 64 * 32) return;
  int e   = i & 7;
  int s   = (i >> 3) & 3;
  int o   = (i >> 5) & 63;
  int ck  = (i >> 11) % NCHNK;
  int tap = i / (NCHNK * 64 * 32);
  int cc = ck * 32 + 8 * (s ^ ((o >> 1) & 3)) + e;
  int c = cc / GF, f = cc - GF * (cc / GF);
  float v = w[(size_t)o * (32 * GF * TAPS) + c * (GF * TAPS) + f * TAPS + tap];
  __bf16 hb = (__bf16)v;
  wt[i] = __builtin_bit_cast(unsigned short, hb);
}

// Block = (b, g, 4-row tile). 4 waves; wave = 2m(32 o) x 2n(32 pos), 32x32x16 MFMA.
// Xs: 8 rows x 64 pos x 32 ch (32KB, XOR-swizzled octets; dummy cols clamped).
// Ws: 5 taps x 64 o x 32 ch (20KB, single buffer, refilled per kh-group via
//     global_load_lds; __syncthreads' implicit vmcnt(0) is the completion wait).
// LDS total 53248 B -> 3 blocks/CU.
__global__ void __launch_bounds__(256, 3)
conv_kernel(const float* __restrict__ x, const unsigned short* __restrict__ wt,
            const float* __restrict__ bias, const int* __restrict__ idx,
            float* __restrict__ out) {
  __shared__ __align__(16) unsigned short Xs[512 * 32];  // 32768 B
  __shared__ __align__(16) unsigned short Ws[5 * 2048];  // 20480 B

  const int bid  = blockIdx.x;        // sequential: consecutive blocks share b -> L3 locality
  const int tile = bid % NTILE;
  const int g    = (bid / NTILE) % 15;
  const int b    = bid / (NTILE * 15);

  const int tid  = threadIdx.x;
  const int lane = tid & 63;
  const int wv   = tid >> 6;          // wave 0..3 = staging channel-octet
  const int l31  = lane & 31;
  const int hi   = lane >> 5;
  const int col  = lane;

  // issue Ws group gi: taps kh*5..kh*5+4 at chunk ck -> Ws[t*2048 ...], linear copy
  auto issue_ws = [&](int gi) {
    const int ckp = gi / 5, khp = gi - 5 * (gi / 5);
#pragma unroll
    for (int t = 0; t < 5; ++t) {
      const int tap = khp * 5 + t;
      glds16(wt + (((size_t)(tap * NCHNK + ckp)) << 11) + tid * 8,
             &Ws[t * 2048 + wv * 512]);
    }
  };
  issue_ws(0);  // in flight during setup + first Xs staging

  // n-frag geometry: wave owns frags {wv, wv+4}; nf = row*2 + half
  int pb[2], colo[2], rowf[2];
#pragma unroll
  for (int i = 0; i < 2; ++i) {
    int nf  = wv + 4 * i;
    rowf[i] = nf >> 1;
    colo[i] = (nf & 1) * 32 + l31;
    pb[i]   = rowf[i] * 64 + (colo[i] < 60 ? colo[i] : 0);  // clamp dummy cols
  }

  // A-read swizzled offsets (tap-invariant): o = m*32+l31, octet = ks*2+hi
  int aoff[2][2];
#pragma unroll
  for (int m = 0; m < 2; ++m)
#pragma unroll
    for (int ks = 0; ks < 2; ++ks)
      aoff[m][ks] = (m * 32 + l31) * 32 + 8 * ((ks * 2 + hi) ^ ((l31 >> 1) & 3));

  f32x16 acc[2][2];
#pragma unroll
  for (int m = 0; m < 2; ++m)
#pragma unroll
    for (int i = 0; i < 2; ++i)
#pragma unroll
      for (int r = 0; r < 16; ++r) acc[m][i][r] = 0.f;

  const int r0 = tile * TROWS;

  for (int gi = 0; gi < NGRP; ++gi) {
    const int ck = gi / 5;
    const int kh = gi - 5 * ck;
    if (kh == 0) {
      // stage Xs(ck): 8 rows x 64 cols, 8 channels/thread (Xs free: all readers
      // of the previous chunk passed the last group's trailing barrier)
      int ib[8];
#pragma unroll
      for (int k = 0; k < 8; ++k) {
        int cc = ck * 32 + 8 * wv + k;
        int c = cc / GF, f = cc - GF * c;
        ib[k] = ((b * 32 + c) * 33 + idx[g * GF + f]) << 12;
      }
#pragma unroll
      for (int row = 0; row < SROWS; ++row) {
        int ga = (r0 + row) * 64 + col;
        u16x8 pk;
#pragma unroll
        for (int k = 0; k < 8; ++k) {
          float v = x[ib[k] + ga];
          pk[k] = __builtin_bit_cast(unsigned short, (__bf16)v);
        }
        int pos = row * 64 + col;
        *reinterpret_cast<u16x8*>(&Xs[pos * 32 + 8 * (wv ^ ((pos >> 1) & 3))]) = pk;
      }
    }
    __syncthreads();  // implicit vmcnt(0): Ws(gi) DMA landed; Xs writes visible

#pragma unroll
    for (int kw = 0; kw < 5; ++kw) {
      u16x8 a[2][2], bf[2][2];
#pragma unroll
      for (int m = 0; m < 2; ++m)
#pragma unroll
        for (int ks = 0; ks < 2; ++ks)
          a[m][ks] = *reinterpret_cast<const u16x8*>(&Ws[kw * 2048 + aoff[m][ks]]);
      const int toff = kh * 64 + kw;
#pragma unroll
      for (int i = 0; i < 2; ++i) {
        int pt = pb[i] + toff;
#pragma unroll
        for (int ks = 0; ks < 2; ++ks)
          bf[i][ks] = *reinterpret_cast<const u16x8*>(
              &Xs[pt * 32 + 8 * ((ks * 2 + hi) ^ ((pt >> 1) & 3))]);
      }
#pragma unroll
      for (int ks = 0; ks < 2; ++ks)
#pragma unroll
        for (int i = 0; i < 2; ++i)
#pragma unroll
          for (int m = 0; m < 2; ++m)
            acc[m][i] = mfma32(a[m][ks], bf[i][ks], acc[m][i]);
    }
    __syncthreads();  // all waves done reading Ws(gi) -> safe to refill
    if (gi + 1 < NGRP) issue_ws(gi + 1);
  }

  // bias into registers (o = m*32 + 4*hi + (r&3) + 8*(r>>2))
  float bv[2][16];
#pragma unroll
  for (int m = 0; m < 2; ++m)
#pragma unroll
    for (int r = 0; r < 16; ++r)
      bv[m][r] = bias[m * 32 + 4 * hi + (r & 3) + 8 * (r >> 2)];

  // epilogue: out[((b*64+o)*15+g)*3600 + (tile*4+row)*60 + col], col<60 valid
#pragma unroll
  for (int i = 0; i < 2; ++i) {
    if (colo[i] < 60) {
      const size_t pbase = (size_t)(tile * TROWS + rowf[i]) * 60 + colo[i];
#pragma unroll
      for (int m = 0; m < 2; ++m)
#pragma unroll
        for (int r = 0; r < 16; ++r) {
          int o = m * 32 + 4 * hi + (r & 3) + 8 * (r >> 2);
          out[((size_t)(b * 64 + o) * 15 + g) * 3600 + pbase] = acc[m][i][r] + bv[m][r];
        }
    }
  }
}

extern "C" void kernel_launch(void* const* d_in, const int* in_sizes, int n_in,
                              void* d_out, int out_size, void* d_ws, size_t ws_size,
                              hipStream_t stream) {
  const float* x      = (const float*)d_in[0];
  const float* weight = (const float*)d_in[1];
  const float* bias   = (const float*)d_in[2];
  const int*   idx    = (const int*)d_in[3];
  float* out = (float*)d_out;
  unsigned short* wt = (unsigned short*)d_ws;  // 25*7*64*32*2 = 716800 B

  wt_kernel<<<(TAPS * NCHNK * 64 * 32 + 255) / 256, 256, 0, stream>>>(weight, wt);
  conv_kernel<<<8 * 15 * NTILE, 256, 0, stream>>>(x, wt, bias, idx, out);
}

// Round 7
// 307.238 us; speedup vs baseline: 3.2714x; 1.1530x over previous
//
#include <hip/hip_runtime.h>
#include <hip/hip_bf16.h>

// ---- problem constants ----
#define GF    7
#define TAPS  25
#define NCHNK 7          // 224/32 channel chunks
#define NTILE 10         // tiles of 6 output rows (exact: 60 = 10*6)
#define TROWS 6
#define SROWS 10         // 6 + 4 halo
#define NPOS  360        // 6*60 positions per tile
#define NF_   23         // ceil(360/16); frag 22 has 8 valid lanes
#define NGRP  35         // NCHNK * 5 kh-groups

typedef __attribute__((ext_vector_type(8)))  __bf16 bf16x8;
typedef __attribute__((ext_vector_type(8)))  unsigned short u16x8;
typedef __attribute__((ext_vector_type(4)))  float f32x4;

__device__ __forceinline__ f32x4 mfma16(u16x8 a, u16x8 b, f32x4 c) {
  return __builtin_amdgcn_mfma_f32_16x16x32_bf16(
      __builtin_bit_cast(bf16x8, a), __builtin_bit_cast(bf16x8, b), c, 0, 0, 0);
}

// async global->LDS, 16B per lane; LDS dest = wave-uniform base + lane*16
__device__ __forceinline__ void glds16(const unsigned short* g, unsigned short* l) {
  __builtin_amdgcn_global_load_lds(
      (__attribute__((address_space(1))) void*)g,
      (__attribute__((address_space(3))) void*)l, 16, 0, 0);
}

// w[o][c][f][kh][kw] f32 -> wt[tap][ck][o][s][e] bf16 with BAKED bank swizzle:
// stored channel cc = ck*32 + 8*(s ^ ((o>>1)&3)) + e
// In-kernel A-read at slot = lk ^ ((lo>>1)&3) is conflict-free with a LINEAR
// LDS copy (global_load_lds-compatible). (o>>1)&3 == (lo>>1)&3 since o = m*16+lo.
__global__ void wt_kernel(const float* __restrict__ w, unsigned short* __restrict__ wt) {
  int i = blockIdx.x * 256 + threadIdx.x;
  if (i >= TAPS * NCHNK * 64 * 32) return;
  int e   = i & 7;
  int s   = (i >> 3) & 3;
  int o   = (i >> 5) & 63;
  int ck  = (i >> 11) % NCHNK;
  int tap = i / (NCHNK * 64 * 32);
  int cc = ck * 32 + 8 * (s ^ ((o >> 1) & 3)) + e;
  int c = cc / GF, f = cc - GF * (cc / GF);
  float v = w[(size_t)o * (32 * GF * TAPS) + c * (GF * TAPS) + f * TAPS + tap];
  __bf16 hb = (__bf16)v;
  wt[i] = __builtin_bit_cast(unsigned short, hb);
}

// Block = (b, g, 6-row tile). 4 waves; wave = 4m(16 o) x <=6n(16 pos) 16x16x32
// -> 24 MFMA per 10 b128 LDS reads (vs 8/8 in R6): LDS and MFMA pipes balanced.
// Xs: 10 rows x 64 pos x 32 ch (40KB, XOR-swizzled octets).
// Ws: 5 taps x 64 o x 32 ch (20KB, single buffer, refilled per kh-group via
//     global_load_lds; __syncthreads' implicit vmcnt(0) is the completion wait).
// LDS total 61440 B -> 2 blocks/CU; (256,2) -> 256-VGPR cap, no spill.
__global__ void __launch_bounds__(256, 2)
conv_kernel(const float* __restrict__ x, const unsigned short* __restrict__ wt,
            const float* __restrict__ bias, const int* __restrict__ idx,
            float* __restrict__ out) {
  __shared__ __align__(16) unsigned short Xs[640 * 32];  // 40960 B
  __shared__ __align__(16) unsigned short Ws[5 * 2048];  // 20480 B

  // XCD-aware bijective swizzle: 1200 = 8 XCDs * 150; all blocks of one image
  // land on one XCD (b = bid/150) -> x-plane L2 reuse across its 150 blocks.
  const int bid0 = blockIdx.x;
  const int bid  = (bid0 & 7) * 150 + (bid0 >> 3);
  const int tile = bid % NTILE;
  const int g    = (bid / NTILE) % 15;
  const int b    = bid / (NTILE * 15);

  const int tid  = threadIdx.x;
  const int lane = tid & 63;
  const int wv   = tid >> 6;     // wave 0..3 = staging channel-octet
  const int lo   = lane & 15;
  const int lk   = lane >> 4;    // 0..3 = k-octet
  const int col  = lane;

  // issue Ws group gi (taps kh*5..kh*5+4 at chunk ck), linear per-wave copy
  auto issue_ws = [&](int gi) {
    const int ckp = gi / 5, khp = gi - 5 * (gi / 5);
#pragma unroll
    for (int t = 0; t < 5; ++t) {
      const int tap = khp * 5 + t;
      glds16(wt + (((size_t)(tap * NCHNK + ckp)) << 11) + tid * 8,
             &Ws[t * 2048 + wv * 512]);
    }
  };
  issue_ws(0);  // in flight during setup + first Xs staging

  // n-frag bases: wave owns frags {wv, wv+4, ..., wv+20} -> (6,6,6,5) balanced
  int p0[6];
  int pvalid = 0;
#pragma unroll
  for (int i = 0; i < 6; ++i) {
    int nf = wv + 4 * i;
    p0[i] = 0;
    if (nf < NF_) {
      int p  = nf * 16 + lo;
      int pc = (p < NPOS) ? p : 0;          // clamp tail lanes; epilogue-guarded
      int ph = pc / 60;
      p0[i] = ph * 64 + (pc - 60 * ph);
      pvalid = i + 1;
    }
  }

  // A-read swizzled offsets (kw-invariant): o = m*16+lo, octet lk
  int aoff[4];
#pragma unroll
  for (int m = 0; m < 4; ++m)
    aoff[m] = (m * 16 + lo) * 32 + 8 * (lk ^ ((lo >> 1) & 3));

  f32x4 acc[4][6];
#pragma unroll
  for (int m = 0; m < 4; ++m)
#pragma unroll
    for (int i = 0; i < 6; ++i) acc[m][i] = f32x4{0.f, 0.f, 0.f, 0.f};

  const int r0 = tile * TROWS;

  for (int gi = 0; gi < NGRP; ++gi) {
    const int ck = gi / 5;
    const int kh = gi - 5 * ck;
    if (kh == 0) {
      // stage Xs(ck): 10 rows x 64 cols, 8 channels/thread (Xs free: previous
      // readers all passed the last group's trailing barrier)
      int ib[8];
#pragma unroll
      for (int k = 0; k < 8; ++k) {
        int cc = ck * 32 + 8 * wv + k;
        int c = cc / GF, f = cc - GF * c;
        ib[k] = ((b * 32 + c) * 33 + idx[g * GF + f]) << 12;
      }
#pragma unroll
      for (int row = 0; row < SROWS; ++row) {
        int ga = (r0 + row) * 64 + col;
        u16x8 pk;
#pragma unroll
        for (int k = 0; k < 8; ++k) {
          float v = x[ib[k] + ga];
          pk[k] = __builtin_bit_cast(unsigned short, (__bf16)v);
        }
        int pos = row * 64 + col;
        *reinterpret_cast<u16x8*>(&Xs[pos * 32 + 8 * (wv ^ ((pos >> 1) & 3))]) = pk;
      }
    }
    __syncthreads();  // implicit vmcnt(0): Ws(gi) DMA landed; Xs writes visible

#pragma unroll
    for (int kw = 0; kw < 5; ++kw) {
      u16x8 a[4], bf[6];
#pragma unroll
      for (int m = 0; m < 4; ++m)
        a[m] = *reinterpret_cast<const u16x8*>(&Ws[kw * 2048 + aoff[m]]);
      const int toff = kh * 64 + kw;
#pragma unroll
      for (int i = 0; i < 6; ++i)
        if (i < pvalid) {
          int pt = p0[i] + toff;
          bf[i] = *reinterpret_cast<const u16x8*>(
              &Xs[pt * 32 + 8 * (lk ^ ((pt >> 1) & 3))]);
        }
#pragma unroll
      for (int i = 0; i < 6; ++i)
        if (i < pvalid)
#pragma unroll
          for (int m = 0; m < 4; ++m)
            acc[m][i] = mfma16(a[m], bf[i], acc[m][i]);
    }
    __syncthreads();  // all waves done reading Ws(gi) -> safe to refill
    if (gi + 1 < NGRP) issue_ws(gi + 1);
  }

  // bias into registers: o = m*16 + 4*lk + v
  float bv[4][4];
#pragma unroll
  for (int m = 0; m < 4; ++m)
#pragma unroll
    for (int v = 0; v < 4; ++v) bv[m][v] = bias[m * 16 + 4 * lk + v];

  // epilogue: out[((b*64+o)*15+g)*3600 + tile*360 + p], p = nf*16+lo < 360
#pragma unroll
  for (int i = 0; i < 6; ++i) {
    if (i < pvalid) {
      int nf = wv + 4 * i;
      int p  = nf * 16 + lo;
      if (p < NPOS) {
        const size_t pb = (size_t)tile * NPOS + p;
#pragma unroll
        for (int m = 0; m < 4; ++m)
#pragma unroll
          for (int v = 0; v < 4; ++v) {
            int o = m * 16 + 4 * lk + v;
            out[((size_t)(b * 64 + o) * 15 + g) * 3600 + pb] = acc[m][i][v] + bv[m][v];
          }
      }
    }
  }
}

extern "C" void kernel_launch(void* const* d_in, const int* in_sizes, int n_in,
                              void* d_out, int out_size, void* d_ws, size_t ws_size,
                              hipStream_t stream) {
  const float* x      = (const float*)d_in[0];
  const float* weight = (const float*)d_in[1];
  const float* bias   = (const float*)d_in[2];
  const int*   idx    = (const int*)d_in[3];
  float* out = (float*)d_out;
  unsigned short* wt = (unsigned short*)d_ws;  // 25*7*64*32*2 = 716800 B

  wt_kernel<<<(TAPS * NCHNK * 64 * 32 + 255) / 256, 256, 0, stream>>>(weight, wt);
  conv_kernel<<<8 * 15 * NTILE, 256, 0, stream>>>(x, wt, bias, idx, out);
}